// Round 5
// baseline (189.566 us; speedup 1.0000x reference)
//
#include <hip/hip_runtime.h>
#include <hip/hip_bf16.h>
#include <stdint.h>
#include <stddef.h>

#define DIM 1024
#define SEQ 2048
#define KF 24

using f32x4  = __attribute__((ext_vector_type(4))) float;
using bf16x8 = __attribute__((ext_vector_type(8))) short;

__device__ __forceinline__ unsigned short f2bf(float f){
  union { float f; unsigned int i; } v; v.f = f;
  unsigned int r = v.i + 0x7FFFu + ((v.i >> 16) & 1u);  // RNE
  return (unsigned short)(r >> 16);
}
// D = a.bf16[0]*b.bf16[0] + a.bf16[1]*b.bf16[1] + c   (V_DOT2_F32_BF16, VOP3P)
__device__ __forceinline__ float dot2bf(unsigned int a, unsigned int b, float c){
  float d;
  asm("v_dot2_f32_bf16 %0, %1, %2, %3" : "=v"(d) : "v"(a), "v"(b), "v"(c));
  return d;
}
__device__ __forceinline__ void gload_lds16(const void* g, void* l){
  __builtin_amdgcn_global_load_lds(
      (const __attribute__((address_space(1))) unsigned int*)g,
      (__attribute__((address_space(3))) unsigned int*)l, 16, 0, 0);
}

// ---------------- prep: x fp32 -> bf16 ----------------
__global__ void k_cvt_x(const float* __restrict__ x, unsigned short* __restrict__ xb){
  int i = blockIdx.x * 256 + threadIdx.x;            // each thread 4 elems
  const float4* x4 = (const float4*)x;
  float4 v = x4[i];
  ushort4 o;
  o.x = f2bf(v.x); o.y = f2bf(v.y); o.z = f2bf(v.z); o.w = f2bf(v.w);
  *(ushort4*)(xb + (size_t)i * 4) = o;
}

// ---------------- prep: M_inputs transpose -> bf16 (B^T, [d][e]) ----------------
__global__ void k_tr_M(const float* __restrict__ Mi, unsigned short* __restrict__ MbT){
  __shared__ float tile[32][33];
  int e0 = blockIdx.y * 32, d0 = blockIdx.x * 32;
  int tx = threadIdx.x, ty = threadIdx.y;            // block (32,8)
  #pragma unroll
  for (int r = 0; r < 32; r += 8)
    tile[ty + r][tx] = Mi[(size_t)(e0 + ty + r) * DIM + d0 + tx];
  __syncthreads();
  #pragma unroll
  for (int r = 0; r < 32; r += 8)
    MbT[(size_t)(d0 + ty + r) * DIM + e0 + tx] = f2bf(tile[tx][ty + r]);
}

// ---------------- prep: pe packed pairs, TRANSPOSED [d][512] ----------------
// pepkT[d][r2] = u32{ lo = 2*phi[4*r2][d], hi = 2*phi[4*r2+2][d] }
__global__ void k_pe(const float* __restrict__ filters, const float* __restrict__ Mf,
                     unsigned int* __restrict__ pepkT){
  int r2 = blockIdx.x * 256 + threadIdx.x;           // 0..511 (grid.x = 2)
  int d  = blockIdx.y;                               // 0..1023
  float a0 = 0.f, a1 = 0.f;
  #pragma unroll
  for (int k = 0; k < KF; ++k){
    float mf = Mf[(size_t)k * DIM + d];              // uniform per block
    a0 += filters[(size_t)(4 * r2)     * KF + k] * mf;
    a1 += filters[(size_t)(4 * r2 + 2) * KF + k] * mf;
  }
  unsigned int lo = f2bf(2.f * a0), hi = f2bf(2.f * a1);
  pepkT[(size_t)d * 512 + r2] = lo | (hi << 16);
}

// ---------------- GEMM: x_proj = x @ M_inputs, epilogue writes BIGRAM ----------------
// Bg[bt][d] (u32) = y[bt][d] | y[bt-2][d]<<16  (bt-2 within same batch, else 0).
// Achieved via: lo half-store at [bt][d] (full u32 with hi=0 when t<2),
//               hi half-store of y at [bt+2][d] when t<2046.
#define BM 128
#define BN 128
#define BKK 64
__global__ void k_gemm(const unsigned short* __restrict__ A,
                       const unsigned short* __restrict__ Bt,
                       unsigned int* __restrict__ Bg){
  __shared__ unsigned short As[BM * BKK];   // 16 KB, XOR-swizzled (unit16B ^= row&7)
  __shared__ unsigned short Bs[BN * BKK];   // 16 KB
  int tid  = threadIdx.x;
  int lane = tid & 63, wave = tid >> 6;
  int wm = wave >> 1, wn = wave & 1;
  int trow0 = blockIdx.x * BM;
  int ncol0 = blockIdx.y * BN;

  f32x4 acc[4][4] = {};

  for (int kt = 0; kt < 1024 / BKK; ++kt){
    __syncthreads();
    #pragma unroll
    for (int g = 0; g < 4; ++g){
      int c  = wave * 4 + g;              // chunk 0..15, 1KB each
      int mr = c * 8 + (lane >> 3);       // tile row this lane stages
      int u  = lane & 7;                  // physical 16B unit within row
      int su = u ^ (mr & 7);              // source (logical) unit
      const unsigned short* srcA = A + (size_t)(trow0 + mr) * 1024 + kt * BKK + su * 8;
      gload_lds16(srcA, (char*)As + c * 1024);
      const unsigned short* srcB = Bt + (size_t)(ncol0 + mr) * 1024 + kt * BKK + su * 8;
      gload_lds16(srcB, (char*)Bs + c * 1024);
    }
    __syncthreads();

    bf16x8 af[4][2], bfr[4][2];
    #pragma unroll
    for (int mi = 0; mi < 4; ++mi){
      int row = wm * 64 + mi * 16 + (lane & 15);
      #pragma unroll
      for (int ks = 0; ks < 2; ++ks){
        int u = ((lane >> 4) + 4 * ks) ^ (row & 7);
        af[mi][ks] = *(const bf16x8*)((const char*)As + row * 128 + u * 16);
      }
    }
    #pragma unroll
    for (int ni = 0; ni < 4; ++ni){
      int row = wn * 64 + ni * 16 + (lane & 15);
      #pragma unroll
      for (int ks = 0; ks < 2; ++ks){
        int u = ((lane >> 4) + 4 * ks) ^ (row & 7);
        bfr[ni][ks] = *(const bf16x8*)((const char*)Bs + row * 128 + u * 16);
      }
    }
    #pragma unroll
    for (int mi = 0; mi < 4; ++mi)
      #pragma unroll
      for (int ni = 0; ni < 4; ++ni)
        #pragma unroll
        for (int ks = 0; ks < 2; ++ks)
          acc[mi][ni] = __builtin_amdgcn_mfma_f32_16x16x32_bf16(
              af[mi][ks], bfr[ni][ks], acc[mi][ni], 0, 0, 0);
  }

  unsigned short* Bh = (unsigned short*)Bg;
  #pragma unroll
  for (int mi = 0; mi < 4; ++mi)
    #pragma unroll
    for (int ni = 0; ni < 4; ++ni){
      int col = ncol0 + wn * 64 + ni * 16 + (lane & 15);
      #pragma unroll
      for (int reg = 0; reg < 4; ++reg){
        int row = trow0 + wm * 64 + mi * 16 + (lane >> 4) * 4 + reg;
        unsigned short y = f2bf(acc[mi][ni][reg]);
        int t = row & 2047;
        size_t idx = (size_t)row * 1024 + col;
        if (t < 2) Bg[idx] = (unsigned int)y;          // lo=y, hi=0 (no y[t-2])
        else       Bh[2 * idx] = y;                    // lo half
        if (t < 2046)
          Bh[2 * ((size_t)(row + 2) * 1024 + col) + 1] = y;  // hi half of bt+2
      }
    }
}

// ---------------- depthwise causal conv via v_dot2_f32_bf16 on bigram pairs ----------
// out[m0+m] = sum_{r<=m0+m} pe[r]*y[m0+m-r].  Chunk c: taps r0=m0-16c..+15,
// window W[t] = Bg_col[16c-14+t] = (y[16c-14+t], y[16c-15+t]); t<14 zero at c=0.
// acc[m] = dot2(pv[q], W[m+14-2q]): zero packing, pe via 2 dwordx4 imm loads.
#define MV 16
__device__ __forceinline__ void dot_block(uint4 a, uint4 b,
                                          const unsigned int* __restrict__ W,
                                          float* __restrict__ acc){
  const unsigned int pq[8] = {a.x, a.y, a.z, a.w, b.x, b.y, b.z, b.w};
  #pragma unroll
  for (int q = 0; q < 8; ++q)
    #pragma unroll
    for (int m = 0; m < MV; ++m)
      acc[m] = dot2bf(pq[q], W[m + 14 - 2 * q], acc[m]);
}

__global__ __launch_bounds__(256, 4)
void k_conv(const unsigned int* __restrict__ Bg,     // [8192][1024] bigram pairs
            const unsigned int* __restrict__ pepkT,  // [1024][512] packed pe pairs
            float* __restrict__ out){                // [4][2048][1024] f32
  int d  = blockIdx.x * 256 + threadIdx.x;  // 0..1023
  int mt = 63 - blockIdx.y;                 // longest-first (LPT)
  int bp = blockIdx.z;                      // 0..7
  int b = bp >> 1, p = bp & 1;
  const unsigned int* bcol = Bg + ((size_t)(b * SEQ + p) * 1024 + d);  // + j*2048
  const unsigned int* pcol = pepkT + (size_t)d * 512;
  int m0 = mt * MV;

  float acc[MV];
  #pragma unroll
  for (int m = 0; m < MV; ++m) acc[m] = 0.f;

  unsigned int W[30];
  #pragma unroll
  for (int t = 0; t < 14; ++t) W[t] = 0u;
  #pragma unroll
  for (int t = 0; t < 16; ++t) W[14 + t] = bcol[(size_t)t * 2048];

  uint4 pva = *(const uint4*)(pcol + (m0 >> 1));
  uint4 pvb = *(const uint4*)(pcol + (m0 >> 1) + 4);

  for (int c = 0; c < mt; ++c){
    // prefetch chunk c+1
    unsigned int nW[16];
    #pragma unroll
    for (int t = 0; t < 16; ++t) nW[t] = bcol[(size_t)(16 * c + 16 + t) * 2048];
    int nr2 = (m0 >> 1) - 8 * (c + 1);
    uint4 npa = *(const uint4*)(pcol + nr2);
    uint4 npb = *(const uint4*)(pcol + nr2 + 4);

    dot_block(pva, pvb, W, acc);

    #pragma unroll
    for (int t = 0; t < 14; ++t) W[t] = W[t + 16];
    #pragma unroll
    for (int t = 0; t < 16; ++t) W[14 + t] = nW[t];
    pva = npa; pvb = npb;
  }
  dot_block(pva, pvb, W, acc);   // last chunk (r0 == 0)

  float* ocol = out + ((size_t)(b * SEQ + p) * 1024 + d);
  #pragma unroll
  for (int m = 0; m < MV; ++m)
    ocol[(size_t)(m0 + m) * 2048] = acc[m];
}

extern "C" void kernel_launch(void* const* d_in, const int* in_sizes, int n_in,
                              void* d_out, int out_size, void* d_ws, size_t ws_size,
                              hipStream_t stream){
  const float* x       = (const float*)d_in[0];
  const float* filters = (const float*)d_in[1];
  const float* Mi      = (const float*)d_in[2];
  const float* Mf      = (const float*)d_in[3];

  char* ws = (char*)d_ws;
  unsigned short* Xb    = (unsigned short*)(ws);                              // 16 MB
  unsigned int*   Bg    = (unsigned int*)  (ws + (size_t)16 * 1024 * 1024);   // 32 MB
  unsigned short* MbT   = (unsigned short*)(ws + (size_t)48 * 1024 * 1024);   //  2 MB
  unsigned int*   pepkT = (unsigned int*)  (ws + (size_t)50 * 1024 * 1024);   //  2 MB
  float* out = (float*)d_out;

  hipLaunchKernelGGL(k_cvt_x, dim3(8192), dim3(256), 0, stream, x, Xb);
  hipLaunchKernelGGL(k_tr_M,  dim3(32, 32), dim3(32, 8), 0, stream, Mi, MbT);
  hipLaunchKernelGGL(k_pe,    dim3(2, 1024), dim3(256), 0, stream, filters, Mf, pepkT);
  hipLaunchKernelGGL(k_gemm,  dim3(64, 8), dim3(256), 0, stream, Xb, MbT, Bg);
  hipLaunchKernelGGL(k_conv,  dim3(4, 64, 8), dim3(256), 0, stream, Bg, pepkT, out);
}